// Round 6
// baseline (19160.449 us; speedup 1.0000x reference)
//
#include <hip/hip_runtime.h>
#include <hip/hip_bf16.h>

// 2-layer GRU, B=128, S=2048, D=H=128, C=10. Inputs fp32.
//
// Phase 1 (all CUs): xp0 = x@Wih0^T + biases (r,z fully folded; n keeps bhh0_n
//   separate), fp16 in d_ws (201 MB).
// Phase 2 (8 persistent WGs x 16 batch rows, 1024 thr = 16 waves = 4/SIMD):
//   layer-pipelined wave specialization with systolic skew:
//     waves 0-7  : layer 0, time t      (Whh0 B-frags in VGPRs, xp0 prefetch)
//     waves 8-15 : layer 1, time t-1    (Whh1 in VGPRs, Wih1 staged in LDS)
//   ONE __syncthreads per step. h: fp32 in regs (C/D layout) + bf16 hi/lo in
//   LDS (A layout), double-buffered by parity. PAD=132 (proven 0-conflict, R4).
//   __launch_bounds__(1024, 4): min 4 waves/EU -> 128-VGPR budget. R5 omitted
//   the 2nd arg -> compiler chose 64 VGPR -> weight frags spilled to scratch
//   -> 19 ms. This is the single fix this round.
// Fallback if ws_size < 201MB: single-kernel path (R2 structure).

using bf16x8 = __attribute__((ext_vector_type(8))) short;
using s16x4  = __attribute__((ext_vector_type(4))) short;
using f32x4  = __attribute__((ext_vector_type(4))) float;

#define S_LEN 2048
#define D_IN  128
#define HID   128
#define B_TOT 128
#define BC    16
#define PAD   132      // LDS row stride in shorts; 66 words == 2 mod 32
#define G3    384
#define M_TOT (B_TOT * S_LEN)

__device__ __forceinline__ float bf2f(short s) {
  unsigned int u = ((unsigned int)(unsigned short)s) << 16;
  float f; __builtin_memcpy(&f, &u, 4); return f;
}
__device__ __forceinline__ short f2bf(float f) {  // RNE
  unsigned int u; __builtin_memcpy(&u, &f, 4);
  u += 0x7fffu + ((u >> 16) & 1u);
  return (short)(u >> 16);
}
__device__ __forceinline__ short f2bf_rtz(float f) {  // truncate (lo-part only)
  unsigned int u; __builtin_memcpy(&u, &f, 4);
  return (short)(u >> 16);
}
__device__ __forceinline__ float fast_sigmoid(float x) {
  return __builtin_amdgcn_rcpf(1.f + __expf(-x));
}
__device__ __forceinline__ float fast_tanh(float x) {
  return 2.f * __builtin_amdgcn_rcpf(1.f + __expf(-2.f * x)) - 1.f;
}
__device__ __forceinline__ f32x4 MFMA(bf16x8 a, bf16x8 b, f32x4 c) {
  return __builtin_amdgcn_mfma_f32_16x16x32_bf16(a, b, c, 0, 0, 0);
}
__device__ __forceinline__ void loadA(bf16x8 (&a)[4], const short* p) {
#pragma unroll
  for (int kq = 0; kq < 4; ++kq) a[kq] = *(const bf16x8*)(p + kq * 32);
}
__device__ __forceinline__ void mm3(const bf16x8 (&a)[4], const bf16x8 (&W)[3][4],
                                    f32x4& r, f32x4& z, f32x4& n) {
#pragma unroll
  for (int kq = 0; kq < 4; ++kq) {
    r = MFMA(a[kq], W[0][kq], r);
    z = MFMA(a[kq], W[1][kq], z);
    n = MFMA(a[kq], W[2][kq], n);
  }
}

// ============================ Phase 1 =====================================
__global__ __launch_bounds__(256, 1) void xp0_gemm(
    const float* __restrict__ x, const float* __restrict__ Wih0,
    const float* __restrict__ bih0, const float* __restrict__ bhh0,
    _Float16* __restrict__ xp0)
{
  __shared__ short wlds[96 * PAD];
  __shared__ float bfold[G3];

  const int tid = threadIdx.x;
  const int w = tid >> 6, lane = tid & 63, nw = lane & 15, quad = lane >> 4;
  const int m0 = blockIdx.x * 64 + w * 16;

  for (int g = tid; g < G3; g += 256)
    bfold[g] = bih0[g] + (g < 256 ? bhh0[g] : 0.f);   // fold bhh for r,z only

  bf16x8 ahi[4], alo[4];
  const int arow = m0 + nw;
#pragma unroll
  for (int kq = 0; kq < 4; ++kq) {
    const float* p = x + (size_t)arow * D_IN + kq * 32 + quad * 8;
    float4 v0 = *(const float4*)p, v1 = *(const float4*)(p + 4);
    float v[8] = {v0.x, v0.y, v0.z, v0.w, v1.x, v1.y, v1.z, v1.w};
#pragma unroll
    for (int e = 0; e < 8; ++e) {
      short h = f2bf(v[e]);
      ahi[kq][e] = h;
      alo[kq][e] = f2bf(v[e] - bf2f(h));
    }
  }

  for (int grp = 0; grp < 4; ++grp) {
    __syncthreads();
    for (int i = tid; i < 96 * 128 / 4; i += 256) {
      const int idx = i * 4, row = idx >> 7, cc = idx & 127;
      float4 v = *(const float4*)(Wih0 + (size_t)(grp * 96 + row) * 128 + cc);
      s16x4 s = { f2bf(v.x), f2bf(v.y), f2bf(v.z), f2bf(v.w) };
      *(s16x4*)&wlds[row * PAD + cc] = s;
    }
    __syncthreads();

    f32x4 acc[6];
#pragma unroll
    for (int i = 0; i < 6; ++i) acc[i] = (f32x4){0.f, 0.f, 0.f, 0.f};
#pragma unroll
    for (int tI = 0; tI < 6; ++tI)
#pragma unroll
      for (int kq = 0; kq < 4; ++kq) {
        bf16x8 b = *(const bf16x8*)&wlds[(tI * 16 + nw) * PAD + kq * 32 + quad * 8];
        acc[tI] = MFMA(ahi[kq], b, acc[tI]);
        acc[tI] = MFMA(alo[kq], b, acc[tI]);
      }

#pragma unroll
    for (int tI = 0; tI < 6; ++tI) {
      const int g = grp * 96 + tI * 16 + nw;
      const float bb = bfold[g];
#pragma unroll
      for (int rr = 0; rr < 4; ++rr) {
        const int m = m0 + quad * 4 + rr;
        xp0[(size_t)m * G3 + g] = (_Float16)(acc[tI][rr] + bb);
      }
    }
  }
}

// ============================ Phase 2 =====================================
__global__ __launch_bounds__(1024, 4) void gru2_rec(
    const _Float16* __restrict__ xp0,
    const float* __restrict__ Whh0, const float* __restrict__ bhh0,
    const float* __restrict__ Wih1, const float* __restrict__ Whh1,
    const float* __restrict__ bih1, const float* __restrict__ bhh1,
    const float* __restrict__ Wout, const float* __restrict__ bout,
    float* __restrict__ out)
{
  __shared__ short H0h[2][BC * PAD], H0l[2][BC * PAD];
  __shared__ short H1h[2][BC * PAD], H1l[2][BC * PAD];
  __shared__ short Wi1S[G3 * PAD];     // Wih1 bf16, row-major, padded

  const int tid  = threadIdx.x;
  const int w    = tid >> 6;          // 0..15
  const int lane = tid & 63;
  const int nw   = lane & 15;
  const int quad = lane >> 4;
  const bool isL1 = (w >= 8);
  const int col  = (w & 7) * 16 + nw; // this lane's hidden-unit column
  const int b0   = blockIdx.x * BC;

  // ---- LDS init: zero h buffers (both parities), stage Wih1 as bf16 ----
  for (int i = tid; i < BC * PAD; i += 1024) {
    H0h[0][i] = 0; H0h[1][i] = 0; H0l[0][i] = 0; H0l[1][i] = 0;
    H1h[0][i] = 0; H1h[1][i] = 0; H1l[0][i] = 0; H1l[1][i] = 0;
  }
  for (int d = tid; d < G3 * HID; d += 1024) {
    const int c = d >> 7, k = d & 127;
    Wi1S[c * PAD + k] = f2bf(Wih1[d]);
  }

  // ---- per-group weights in VGPRs: L0 -> Whh0, L1 -> Whh1 ----
  const float* Wsrc = isL1 ? Whh1 : Whh0;
  bf16x8 WF[3][4];
#pragma unroll
  for (int g = 0; g < 3; ++g)
#pragma unroll
    for (int kq = 0; kq < 4; ++kq) {
      const size_t o = (size_t)(g * 128 + col) * HID + kq * 32 + quad * 8;
#pragma unroll
      for (int e = 0; e < 8; ++e) WF[g][kq][e] = f2bf(Wsrc[o + e]);
    }

  // ---- biases ----
  float c_b0nh = 0.f, c_b1r = 0.f, c_b1z = 0.f, c_b1ni = 0.f, c_b1nh = 0.f;
  if (!isL1) {
    c_b0nh = bhh0[256 + col];
  } else {
    c_b1r  = bih1[col]       + bhh1[col];
    c_b1z  = bih1[128 + col] + bhh1[128 + col];
    c_b1ni = bih1[256 + col];
    c_b1nh = bhh1[256 + col];
  }

  // ---- L0 xp0 prefetch state: uniform pointer + per-lane offsets ----
  const _Float16* pt = xp0 + (size_t)b0 * S_LEN * G3;   // advances G3/step
  int xoff[4];
#pragma unroll
  for (int rr = 0; rr < 4; ++rr)
    xoff[rr] = (quad * 4 + rr) * S_LEN * G3 + col;      // + g*128 via imm

  f32x4 hreg = {0.f, 0.f, 0.f, 0.f};   // own-layer h state (4 rows, this col)
  float PA[12], PB[12];

  if (!isL1) {  // preload P[t=0]
#pragma unroll
    for (int g = 0; g < 3; ++g)
#pragma unroll
      for (int rr = 0; rr < 4; ++rr)
        PA[g * 4 + rr] = (float)pt[xoff[rr] + g * 128];
    pt += G3;
  }
  __syncthreads();

  const int aoff = nw * PAD + quad * 8;
  const int hwo  = quad * 4 * PAD + col;   // h write base (row=quad*4)

  // ---- layer-0 step: h0[t] from H0[rp], write H0[wp]; uses Pu, prefetches Pl
  auto l0_step = [&](int rp, int wp, const float (&Pu)[12], float (&Pl)[12],
                     bool pf) {
    if (pf) {
#pragma unroll
      for (int g = 0; g < 3; ++g)
#pragma unroll
        for (int rr = 0; rr < 4; ++rr)
          Pl[g * 4 + rr] = (float)pt[xoff[rr] + g * 128];
      pt += G3;
    }
    f32x4 ar, az, ahn = {0.f, 0.f, 0.f, 0.f};
#pragma unroll
    for (int rr = 0; rr < 4; ++rr) { ar[rr] = Pu[rr]; az[rr] = Pu[4 + rr]; }
    bf16x8 a[4];
    loadA(a, &H0h[rp][aoff]); mm3(a, WF, ar, az, ahn);
    loadA(a, &H0l[rp][aoff]); mm3(a, WF, ar, az, ahn);
#pragma unroll
    for (int rr = 0; rr < 4; ++rr) {
      float r = fast_sigmoid(ar[rr]);
      float z = fast_sigmoid(az[rr]);
      float n = fast_tanh(fmaf(r, ahn[rr] + c_b0nh, Pu[8 + rr]));
      float h = n + z * (hreg[rr] - n);
      hreg[rr] = h;
      short hi = f2bf(h);
      H0h[wp][hwo + rr * PAD] = hi;
      H0l[wp][hwo + rr * PAD] = f2bf_rtz(h - bf2f(hi));
    }
  };

  // ---- layer-1 step (time t-1): reads H0[rp] (h0[t-1]) and H1[wp] (h1[t-2]),
  //      writes H1[rp] (h1[t-1])
  auto l1_step = [&](int rp, int wp) {
    bf16x8 ah[4], al[4];
    loadA(ah, &H0h[rp][aoff]);
    loadA(al, &H0l[rp][aoff]);
    f32x4 br  = {c_b1r,  c_b1r,  c_b1r,  c_b1r};
    f32x4 bz  = {c_b1z,  c_b1z,  c_b1z,  c_b1z};
    f32x4 bxn = {c_b1ni, c_b1ni, c_b1ni, c_b1ni};
#pragma unroll
    for (int g = 0; g < 3; ++g) {
      bf16x8 wb[4];
#pragma unroll
      for (int kq = 0; kq < 4; ++kq)
        wb[kq] = *(const bf16x8*)&Wi1S[(g * 128 + col) * PAD + kq * 32 + quad * 8];
      f32x4& dst = (g == 0) ? br : (g == 1) ? bz : bxn;
#pragma unroll
      for (int kq = 0; kq < 4; ++kq) {
        dst = MFMA(ah[kq], wb[kq], dst);
        dst = MFMA(al[kq], wb[kq], dst);
      }
    }
    f32x4 bhn = {0.f, 0.f, 0.f, 0.f};
    loadA(ah, &H1h[wp][aoff]); mm3(ah, WF, br, bz, bhn);
    loadA(al, &H1l[wp][aoff]); mm3(al, WF, br, bz, bhn);
#pragma unroll
    for (int rr = 0; rr < 4; ++rr) {
      float r = fast_sigmoid(br[rr]);
      float z = fast_sigmoid(bz[rr]);
      float n = fast_tanh(fmaf(r, bhn[rr] + c_b1nh, bxn[rr]));
      float h = n + z * (hreg[rr] - n);
      hreg[rr] = h;
      short hi = f2bf(h);
      H1h[rp][hwo + rr * PAD] = hi;
      H1l[rp][hwo + rr * PAD] = f2bf_rtz(h - bf2f(hi));
    }
  };

  // ---- main loop: iter t: L0 does time t, L1 does time t-1 ----
  // parities: rp = (t+1)&1, wp = t&1
  if (!isL1) l0_step(1, 0, PA, PB, true);          // t=0 peel (L1 idle)
  __syncthreads();
  for (int t = 1; t + 1 < S_LEN; t += 2) {
    if (!isL1) l0_step(0, 1, PB, PA, true); else l1_step(0, 1);   // t odd
    __syncthreads();
    if (!isL1) l0_step(1, 0, PA, PB, true); else l1_step(1, 0);   // t+1 even
    __syncthreads();
  }
  if (!isL1) l0_step(0, 1, PB, PA, false); else l1_step(0, 1);    // t=2047
  __syncthreads();
  if (isL1) l1_step(1, 0);                                        // t=2048: L1 tail
  __syncthreads();

  // ---- logits from final h1 = H1[1] ----
  if (tid < BC * 10) {
    const int b = tid / 10, c = tid % 10;
    float s = bout[c];
    const short* hh = &H1h[1][b * PAD];
    const short* hl = &H1l[1][b * PAD];
#pragma unroll 8
    for (int k = 0; k < HID; ++k)
      s += (bf2f(hh[k]) + bf2f(hl[k])) * Wout[c * HID + k];
    out[(size_t)(b0 + b) * 10 + c] = s;
  }
}

// ==================== Fallback: single-kernel path (fp32) ==================
template<bool NSEP>
__device__ __forceinline__ void mm6(const bf16x8 (&a)[4], const bf16x8 (&W)[6][4],
                                    f32x4 (&acc)[6], f32x4 (&accn)[2]) {
#pragma unroll
  for (int tI = 0; tI < 6; ++tI)
#pragma unroll
    for (int kq = 0; kq < 4; ++kq) {
      if (NSEP && tI >= 4) accn[tI - 4] = MFMA(a[kq], W[tI][kq], accn[tI - 4]);
      else                 acc[tI]      = MFMA(a[kq], W[tI][kq], acc[tI]);
    }
}

__global__ __launch_bounds__(256, 1) void gru2_v1(
    const float* __restrict__ x,
    const float* __restrict__ Wih0, const float* __restrict__ Whh0,
    const float* __restrict__ bih0, const float* __restrict__ bhh0,
    const float* __restrict__ Wih1, const float* __restrict__ Whh1,
    const float* __restrict__ bih1, const float* __restrict__ bhh1,
    const float* __restrict__ Wout, const float* __restrict__ bout,
    float* __restrict__ out)
{
  __shared__ short h0hi[2][16 * PAD], h0lo[2][16 * PAD];
  __shared__ short h1hi[2][16 * PAD], h1lo[2][16 * PAD];
  __shared__ short xbhi[2][16 * PAD], xblo[2][16 * PAD];

  const int tid = threadIdx.x, w = tid >> 6, lane = tid & 63;
  const int nw = lane & 15, quad = lane >> 4, u0 = w * 32;
  const int b0 = blockIdx.x * 16;

  for (int i = tid; i < 16 * PAD; i += 256) {
    h0hi[0][i] = 0; h0lo[0][i] = 0; h1hi[0][i] = 0; h1lo[0][i] = 0;
  }
  const size_t xelem = (size_t)(b0 + (tid >> 4)) * (size_t)(S_LEN * D_IN) + (size_t)((tid & 15) * 8);
  const int xsoff = (tid >> 4) * PAD + (tid & 15) * 8;

  auto load_x = [&](int t, bf16x8& xhi, bf16x8& xlo) {
    const size_t o = xelem + (size_t)t * D_IN;
    float4 v0 = *(const float4*)(x + o), v1 = *(const float4*)(x + o + 4);
    float v[8] = {v0.x, v0.y, v0.z, v0.w, v1.x, v1.y, v1.z, v1.w};
#pragma unroll
    for (int e = 0; e < 8; ++e) {
      short h = f2bf(v[e]); xhi[e] = h; xlo[e] = f2bf(v[e] - bf2f(h));
    }
  };
  { bf16x8 xh, xl; load_x(0, xh, xl);
    *(bf16x8*)&xbhi[0][xsoff] = xh; *(bf16x8*)&xblo[0][xsoff] = xl; }

  float brz0[4], bn0[4], brz1[4], bn1[4];
#pragma unroll
  for (int i = 0; i < 2; ++i) {
    const int c = u0 + i * 16 + nw;
    brz0[i] = bih0[c] + bhh0[c];     brz0[2 + i] = bih0[128 + c] + bhh0[128 + c];
    bn0[i] = bih0[256 + c];          bn0[2 + i] = bhh0[256 + c];
    brz1[i] = bih1[c] + bhh1[c];     brz1[2 + i] = bih1[128 + c] + bhh1[128 + c];
    bn1[i] = bih1[256 + c];          bn1[2 + i] = bhh1[256 + c];
  }

  bf16x8 W0[6][4], Wh0f[6][4], W1[6][4], Wh1f[6][4];
#pragma unroll
  for (int tI = 0; tI < 6; ++tI) {
    const int rb = (tI >> 1) * 128 + u0 + (tI & 1) * 16 + nw;
#pragma unroll
    for (int kq = 0; kq < 4; ++kq) {
      const size_t o = (size_t)rb * HID + kq * 32 + quad * 8;
#pragma unroll
      for (int e = 0; e < 8; ++e) {
        W0[tI][kq][e] = f2bf(Wih0[o + e]);  Wh0f[tI][kq][e] = f2bf(Whh0[o + e]);
        W1[tI][kq][e] = f2bf(Wih1[o + e]);  Wh1f[tI][kq][e] = f2bf(Whh1[o + e]);
      }
    }
  }

  f32x4 h0reg[2] = {{0,0,0,0},{0,0,0,0}}, h1reg[2] = {{0,0,0,0},{0,0,0,0}};
  const f32x4 ZV = {0.f, 0.f, 0.f, 0.f};
  __syncthreads();
  const int aoff = nw * PAD + quad * 8;

  auto gates = [&](const f32x4 (&acc)[6], const f32x4 (&accn)[2], f32x4 (&hreg)[2],
                   const float (&brz)[4], const float (&bn)[4],
                   short* dhi, short* dlo) {
#pragma unroll
    for (int i = 0; i < 2; ++i) {
      const int c = u0 + i * 16 + nw;
#pragma unroll
      for (int rr = 0; rr < 4; ++rr) {
        float rv = fast_sigmoid(acc[i][rr] + brz[i]);
        float zv = fast_sigmoid(acc[2 + i][rr] + brz[2 + i]);
        float nv = fast_tanh((acc[4 + i][rr] + bn[i]) + rv * (accn[i][rr] + bn[2 + i]));
        float h = (1.f - zv) * nv + zv * hreg[i][rr];
        hreg[i][rr] = h;
        short hi = f2bf(h);
        const int row = quad * 4 + rr;
        dhi[row * PAD + c] = hi;
        dlo[row * PAD + c] = f2bf(h - bf2f(hi));
      }
    }
  };

  for (int t = 0; t < S_LEN; ++t) {
    const int pr = t & 1, pw = pr ^ 1;
    const int t1 = (t + 1 < S_LEN) ? t + 1 : t;
    bf16x8 xh, xl; load_x(t1, xh, xl);

    f32x4 acc[6], accn[2];
#pragma unroll
    for (int i = 0; i < 6; ++i) acc[i] = ZV;
#pragma unroll
    for (int i = 0; i < 2; ++i) accn[i] = ZV;
    bf16x8 a[4];
    loadA(a, &xbhi[pr][aoff]); mm6<false>(a, W0, acc, accn);
    loadA(a, &xblo[pr][aoff]); mm6<false>(a, W0, acc, accn);
    loadA(a, &h0hi[pr][aoff]); mm6<true >(a, Wh0f, acc, accn);
    loadA(a, &h0lo[pr][aoff]); mm6<true >(a, Wh0f, acc, accn);
    gates(acc, accn, h0reg, brz0, bn0, h0hi[pw], h0lo[pw]);
    __syncthreads();

#pragma unroll
    for (int i = 0; i < 6; ++i) acc[i] = ZV;
#pragma unroll
    for (int i = 0; i < 2; ++i) accn[i] = ZV;
    loadA(a, &h0hi[pw][aoff]); mm6<false>(a, W1, acc, accn);
    loadA(a, &h0lo[pw][aoff]); mm6<false>(a, W1, acc, accn);
    loadA(a, &h1hi[pr][aoff]); mm6<true >(a, Wh1f, acc, accn);
    loadA(a, &h1lo[pr][aoff]); mm6<true >(a, Wh1f, acc, accn);
    *(bf16x8*)&xbhi[pw][xsoff] = xh;
    *(bf16x8*)&xblo[pw][xsoff] = xl;
    gates(acc, accn, h1reg, brz1, bn1, h1hi[pw], h1lo[pw]);
    __syncthreads();
  }

  if (tid < 16 * 10) {
    const int b = tid / 10, c = tid % 10;
    float s = bout[c];
    const short* hh = &h1hi[0][b * PAD];
    const short* hl = &h1lo[0][b * PAD];
#pragma unroll 8
    for (int k = 0; k < HID; ++k)
      s += (bf2f(hh[k]) + bf2f(hl[k])) * Wout[c * HID + k];
    out[(size_t)(b0 + b) * 10 + c] = s;
  }
}

// ============================ Host =========================================
extern "C" void kernel_launch(void* const* d_in, const int* in_sizes, int n_in,
                              void* d_out, int out_size, void* d_ws, size_t ws_size,
                              hipStream_t stream) {
  (void)in_sizes; (void)n_in; (void)out_size;
  const float* x    = (const float*)d_in[0];
  const float* Wih0 = (const float*)d_in[1];
  const float* Whh0 = (const float*)d_in[2];
  const float* bih0 = (const float*)d_in[3];
  const float* bhh0 = (const float*)d_in[4];
  const float* Wih1 = (const float*)d_in[5];
  const float* Whh1 = (const float*)d_in[6];
  const float* bih1 = (const float*)d_in[7];
  const float* bhh1 = (const float*)d_in[8];
  const float* Wout = (const float*)d_in[9];
  const float* bout = (const float*)d_in[10];
  float* out = (float*)d_out;

  const size_t XPB = (size_t)M_TOT * G3 * sizeof(_Float16);  // 201 MB
  if (ws_size >= XPB) {
    xp0_gemm<<<dim3(M_TOT / 64), dim3(256), 0, stream>>>(
        x, Wih0, bih0, bhh0, (_Float16*)d_ws);
    gru2_rec<<<dim3(B_TOT / BC), dim3(1024), 0, stream>>>(
        (const _Float16*)d_ws, Whh0, bhh0, Wih1, Whh1, bih1, bhh1, Wout, bout, out);
  } else {
    gru2_v1<<<dim3(B_TOT / 16), dim3(256), 0, stream>>>(
        x, Wih0, Whh0, bih0, bhh0, Wih1, Whh1, bih1, bhh1, Wout, bout, out);
  }
}

// Round 7
// 6692.732 us; speedup vs baseline: 2.8629x; 2.8629x over previous
//
#include <hip/hip_runtime.h>
#include <hip/hip_bf16.h>

// 2-layer GRU, B=128, S=2048, D=H=128, C=10. Inputs fp32.
//
// Phase 1 (all CUs): xp0 = x@Wih0^T (+ biases; r,z fully folded, n keeps
//   bhh0_n separate), fp16 in d_ws (201 MB).
// Phase 2 (8 persistent WGs x 16 batch rows, 512 thr = 8 waves = 2/SIMD,
//   __launch_bounds__(512,2) -> 128-VGPR arch budget, PROVEN no-spill in R3):
//   each wave owns 16 hidden cols of BOTH layers (r/z/n weight rows ->
//   gate math lane-local in MFMA C/D layout). h fp32 in regs, bf16 (hi-only)
//   in LDS (A layout), parity double-buffered, 2 barriers/step.
//   vs R3: lo-streams dropped (72 -> 36 MFMA/wave/step; MFMA pipe was 44% of
//   the step), PAD=132 (R4: 0 bank conflicts), Whh1 GEMM hoisted to phase A,
//   2-step unrolled loop (PA/PB swap), exact fp32 logits epilogue.
// Fallback if ws_size < 201MB: single-kernel R2 path.

using bf16x8 = __attribute__((ext_vector_type(8))) short;
using s16x4  = __attribute__((ext_vector_type(4))) short;
using f32x4  = __attribute__((ext_vector_type(4))) float;

#define S_LEN 2048
#define D_IN  128
#define HID   128
#define B_TOT 128
#define BC    16
#define PAD   132      // LDS row stride in shorts; 66 words == 2 mod 32
#define G3    384
#define M_TOT (B_TOT * S_LEN)

__device__ __forceinline__ float bf2f(short s) {
  unsigned int u = ((unsigned int)(unsigned short)s) << 16;
  float f; __builtin_memcpy(&f, &u, 4); return f;
}
__device__ __forceinline__ short f2bf(float f) {  // RNE
  unsigned int u; __builtin_memcpy(&u, &f, 4);
  u += 0x7fffu + ((u >> 16) & 1u);
  return (short)(u >> 16);
}
__device__ __forceinline__ float fast_sigmoid(float x) {
  return __builtin_amdgcn_rcpf(1.f + __expf(-x));
}
__device__ __forceinline__ float fast_tanh(float x) {
  return 2.f * __builtin_amdgcn_rcpf(1.f + __expf(-2.f * x)) - 1.f;
}
__device__ __forceinline__ f32x4 MFMA(bf16x8 a, bf16x8 b, f32x4 c) {
  return __builtin_amdgcn_mfma_f32_16x16x32_bf16(a, b, c, 0, 0, 0);
}
__device__ __forceinline__ void loadA(bf16x8 (&a)[4], const short* p) {
#pragma unroll
  for (int kq = 0; kq < 4; ++kq) a[kq] = *(const bf16x8*)(p + kq * 32);
}
__device__ __forceinline__ void mm3(const bf16x8 (&a)[4], const bf16x8 (&W)[3][4],
                                    f32x4& r, f32x4& z, f32x4& n) {
#pragma unroll
  for (int kq = 0; kq < 4; ++kq) {
    r = MFMA(a[kq], W[0][kq], r);
    z = MFMA(a[kq], W[1][kq], z);
    n = MFMA(a[kq], W[2][kq], n);
  }
}

// ============================ Phase 1 =====================================
__global__ __launch_bounds__(256, 1) void xp0_gemm(
    const float* __restrict__ x, const float* __restrict__ Wih0,
    const float* __restrict__ bih0, const float* __restrict__ bhh0,
    _Float16* __restrict__ xp0)
{
  __shared__ short wlds[96 * PAD];
  __shared__ float bfold[G3];

  const int tid = threadIdx.x;
  const int w = tid >> 6, lane = tid & 63, nw = lane & 15, quad = lane >> 4;
  const int m0 = blockIdx.x * 64 + w * 16;

  for (int g = tid; g < G3; g += 256)
    bfold[g] = bih0[g] + (g < 256 ? bhh0[g] : 0.f);   // fold bhh for r,z only

  bf16x8 ahi[4], alo[4];
  const int arow = m0 + nw;
#pragma unroll
  for (int kq = 0; kq < 4; ++kq) {
    const float* p = x + (size_t)arow * D_IN + kq * 32 + quad * 8;
    float4 v0 = *(const float4*)p, v1 = *(const float4*)(p + 4);
    float v[8] = {v0.x, v0.y, v0.z, v0.w, v1.x, v1.y, v1.z, v1.w};
#pragma unroll
    for (int e = 0; e < 8; ++e) {
      short h = f2bf(v[e]);
      ahi[kq][e] = h;
      alo[kq][e] = f2bf(v[e] - bf2f(h));
    }
  }

  for (int grp = 0; grp < 4; ++grp) {
    __syncthreads();
    for (int i = tid; i < 96 * 128 / 4; i += 256) {
      const int idx = i * 4, row = idx >> 7, cc = idx & 127;
      float4 v = *(const float4*)(Wih0 + (size_t)(grp * 96 + row) * 128 + cc);
      s16x4 s = { f2bf(v.x), f2bf(v.y), f2bf(v.z), f2bf(v.w) };
      *(s16x4*)&wlds[row * PAD + cc] = s;
    }
    __syncthreads();

    f32x4 acc[6];
#pragma unroll
    for (int i = 0; i < 6; ++i) acc[i] = (f32x4){0.f, 0.f, 0.f, 0.f};
#pragma unroll
    for (int tI = 0; tI < 6; ++tI)
#pragma unroll
      for (int kq = 0; kq < 4; ++kq) {
        bf16x8 b = *(const bf16x8*)&wlds[(tI * 16 + nw) * PAD + kq * 32 + quad * 8];
        acc[tI] = MFMA(ahi[kq], b, acc[tI]);
        acc[tI] = MFMA(alo[kq], b, acc[tI]);
      }

#pragma unroll
    for (int tI = 0; tI < 6; ++tI) {
      const int g = grp * 96 + tI * 16 + nw;
      const float bb = bfold[g];
#pragma unroll
      for (int rr = 0; rr < 4; ++rr) {
        const int m = m0 + quad * 4 + rr;
        xp0[(size_t)m * G3 + g] = (_Float16)(acc[tI][rr] + bb);
      }
    }
  }
}

// ============================ Phase 2 =====================================
__global__ __launch_bounds__(512, 2) void gru2_rec(
    const _Float16* __restrict__ xp0,
    const float* __restrict__ Whh0, const float* __restrict__ bhh0,
    const float* __restrict__ Wih1, const float* __restrict__ Whh1,
    const float* __restrict__ bih1, const float* __restrict__ bhh1,
    const float* __restrict__ Wout, const float* __restrict__ bout,
    float* __restrict__ out)
{
  __shared__ short H0[2][BC * PAD], H1[2][BC * PAD];   // h bf16 (hi), A layout
  __shared__ float HF[BC][HID];                        // final h1 fp32 (epilogue)

  const int tid  = threadIdx.x;
  const int w    = tid >> 6;        // 0..7
  const int lane = tid & 63;
  const int nw   = lane & 15;
  const int quad = lane >> 4;
  const int col  = w * 16 + nw;     // this lane's hidden-unit column
  const int b0   = blockIdx.x * BC;

  for (int i = tid; i < BC * PAD; i += 512) {
    H0[0][i] = 0; H0[1][i] = 0; H1[0][i] = 0; H1[1][i] = 0;
  }

  // biases (layer-0 input-side + r/z hidden-side folded into xp0 already)
  const float c_b0nh = bhh0[256 + col];
  const float c_b1r  = bih1[col]       + bhh1[col];
  const float c_b1z  = bih1[128 + col] + bhh1[128 + col];
  const float c_b1ni = bih1[256 + col];
  const float c_b1nh = bhh1[256 + col];

  // VGPR-resident weight B-frags (bf16 hi), 3 matrices x 3 gate tiles
  bf16x8 Wh0[3][4], Wi1[3][4], Wh1[3][4];
#pragma unroll
  for (int g = 0; g < 3; ++g)
#pragma unroll
    for (int kq = 0; kq < 4; ++kq) {
      const size_t o = (size_t)(g * 128 + col) * HID + kq * 32 + quad * 8;
#pragma unroll
      for (int e = 0; e < 8; ++e) {
        Wh0[g][kq][e] = f2bf(Whh0[o + e]);
        Wi1[g][kq][e] = f2bf(Wih1[o + e]);
        Wh1[g][kq][e] = f2bf(Whh1[o + e]);
      }
    }

  // xp0 addressing: lane covers rows quad*4+rr (all valid, BC=16)
  size_t xbase[4];
#pragma unroll
  for (int rr = 0; rr < 4; ++rr)
    xbase[rr] = (size_t)(b0 + quad * 4 + rr) * S_LEN * G3 + col;

  float PA[12], PB[12];
#pragma unroll
  for (int g = 0; g < 3; ++g)
#pragma unroll
    for (int rr = 0; rr < 4; ++rr)
      PA[g * 4 + rr] = (float)xp0[xbase[rr] + g * 128];

  f32x4 h0r = {0.f, 0.f, 0.f, 0.f}, h1r = {0.f, 0.f, 0.f, 0.f};
  __syncthreads();

  const int aoff = nw * PAD + quad * 8;
  const int hwo  = quad * 4 * PAD + col;

  // one GRU step: read parity pr, write parity pr^1; uses Pu, prefetches tn->Pl
  auto step = [&](int pr, const float (&Pu)[12], float (&Pl)[12], int tn) {
    const int pw = pr ^ 1;
    // prefetch next xp (in flight under phase-A compute)
#pragma unroll
    for (int g = 0; g < 3; ++g)
#pragma unroll
      for (int rr = 0; rr < 4; ++rr)
        Pl[g * 4 + rr] = (float)xp0[xbase[rr] + (size_t)tn * G3 + g * 128];

    // ---- phase A: Whh0 x h0[t-1]  and  Whh1 x h1[t-1] ----
    f32x4 ar, az, ahn = {0.f, 0.f, 0.f, 0.f};
#pragma unroll
    for (int rr = 0; rr < 4; ++rr) { ar[rr] = Pu[rr]; az[rr] = Pu[4 + rr]; }
    f32x4 br  = {c_b1r, c_b1r, c_b1r, c_b1r};
    f32x4 bz  = {c_b1z, c_b1z, c_b1z, c_b1z};
    f32x4 bhn = {0.f, 0.f, 0.f, 0.f};
    bf16x8 a[4];
    loadA(a, &H0[pr][aoff]); mm3(a, Wh0, ar, az, ahn);
    loadA(a, &H1[pr][aoff]); mm3(a, Wh1, br, bz, bhn);

    // layer-0 gates -> h0_new (fp32 regs + bf16 LDS)
#pragma unroll
    for (int rr = 0; rr < 4; ++rr) {
      float r = fast_sigmoid(ar[rr]);
      float z = fast_sigmoid(az[rr]);
      float n = fast_tanh(fmaf(r, ahn[rr] + c_b0nh, Pu[8 + rr]));
      float h = n + z * (h0r[rr] - n);
      h0r[rr] = h;
      H0[pw][hwo + rr * PAD] = f2bf(h);
    }
    __syncthreads();   // h0_new visible

    // ---- phase B: Wih1 x h0_new (r,z accumulate onto Whh1 part) ----
    f32x4 bxn = {c_b1ni, c_b1ni, c_b1ni, c_b1ni};
    loadA(a, &H0[pw][aoff]); mm3(a, Wi1, br, bz, bxn);

#pragma unroll
    for (int rr = 0; rr < 4; ++rr) {
      float r = fast_sigmoid(br[rr]);
      float z = fast_sigmoid(bz[rr]);
      float n = fast_tanh(fmaf(r, bhn[rr] + c_b1nh, bxn[rr]));
      float h = n + z * (h1r[rr] - n);
      h1r[rr] = h;
      H1[pw][hwo + rr * PAD] = f2bf(h);
    }
    __syncthreads();   // h1_new visible; parity WAR safe
  };

  for (int t = 0; t < S_LEN; t += 2) {
    const int t1 = t + 1;                              // <= 2047
    const int t2 = (t + 2 < S_LEN) ? t + 2 : S_LEN - 1;
    step(0, PA, PB, t1);
    step(1, PB, PA, t2);
  }

  // ---- exact fp32 h1 for logits ----
#pragma unroll
  for (int rr = 0; rr < 4; ++rr)
    HF[quad * 4 + rr][col] = h1r[rr];
  __syncthreads();

  if (tid < BC * 10) {
    const int b = tid / 10, c = tid % 10;
    float s = bout[c];
    const float* hh = HF[b];
    const float* wr = Wout + c * HID;
#pragma unroll 8
    for (int k = 0; k < HID; ++k)
      s = fmaf(hh[k], wr[k], s);
    out[(size_t)(b0 + b) * 10 + c] = s;
  }
}

// ==================== Fallback: single-kernel path (fp32) ==================
template<bool NSEP>
__device__ __forceinline__ void mm6(const bf16x8 (&a)[4], const bf16x8 (&W)[6][4],
                                    f32x4 (&acc)[6], f32x4 (&accn)[2]) {
#pragma unroll
  for (int tI = 0; tI < 6; ++tI)
#pragma unroll
    for (int kq = 0; kq < 4; ++kq) {
      if (NSEP && tI >= 4) accn[tI - 4] = MFMA(a[kq], W[tI][kq], accn[tI - 4]);
      else                 acc[tI]      = MFMA(a[kq], W[tI][kq], acc[tI]);
    }
}

__global__ __launch_bounds__(256, 1) void gru2_v1(
    const float* __restrict__ x,
    const float* __restrict__ Wih0, const float* __restrict__ Whh0,
    const float* __restrict__ bih0, const float* __restrict__ bhh0,
    const float* __restrict__ Wih1, const float* __restrict__ Whh1,
    const float* __restrict__ bih1, const float* __restrict__ bhh1,
    const float* __restrict__ Wout, const float* __restrict__ bout,
    float* __restrict__ out)
{
  __shared__ short h0hi[2][16 * PAD], h0lo[2][16 * PAD];
  __shared__ short h1hi[2][16 * PAD], h1lo[2][16 * PAD];
  __shared__ short xbhi[2][16 * PAD], xblo[2][16 * PAD];

  const int tid = threadIdx.x, w = tid >> 6, lane = tid & 63;
  const int nw = lane & 15, quad = lane >> 4, u0 = w * 32;
  const int b0 = blockIdx.x * 16;

  for (int i = tid; i < 16 * PAD; i += 256) {
    h0hi[0][i] = 0; h0lo[0][i] = 0; h1hi[0][i] = 0; h1lo[0][i] = 0;
  }
  const size_t xelem = (size_t)(b0 + (tid >> 4)) * (size_t)(S_LEN * D_IN) + (size_t)((tid & 15) * 8);
  const int xsoff = (tid >> 4) * PAD + (tid & 15) * 8;

  auto load_x = [&](int t, bf16x8& xhi, bf16x8& xlo) {
    const size_t o = xelem + (size_t)t * D_IN;
    float4 v0 = *(const float4*)(x + o), v1 = *(const float4*)(x + o + 4);
    float v[8] = {v0.x, v0.y, v0.z, v0.w, v1.x, v1.y, v1.z, v1.w};
#pragma unroll
    for (int e = 0; e < 8; ++e) {
      short h = f2bf(v[e]); xhi[e] = h; xlo[e] = f2bf(v[e] - bf2f(h));
    }
  };
  { bf16x8 xh, xl; load_x(0, xh, xl);
    *(bf16x8*)&xbhi[0][xsoff] = xh; *(bf16x8*)&xblo[0][xsoff] = xl; }

  float brz0[4], bn0[4], brz1[4], bn1[4];
#pragma unroll
  for (int i = 0; i < 2; ++i) {
    const int c = u0 + i * 16 + nw;
    brz0[i] = bih0[c] + bhh0[c];     brz0[2 + i] = bih0[128 + c] + bhh0[128 + c];
    bn0[i] = bih0[256 + c];          bn0[2 + i] = bhh0[256 + c];
    brz1[i] = bih1[c] + bhh1[c];     brz1[2 + i] = bih1[128 + c] + bhh1[128 + c];
    bn1[i] = bih1[256 + c];          bn1[2 + i] = bhh1[256 + c];
  }

  bf16x8 W0[6][4], Wh0f[6][4], W1[6][4], Wh1f[6][4];
#pragma unroll
  for (int tI = 0; tI < 6; ++tI) {
    const int rb = (tI >> 1) * 128 + u0 + (tI & 1) * 16 + nw;
#pragma unroll
    for (int kq = 0; kq < 4; ++kq) {
      const size_t o = (size_t)rb * HID + kq * 32 + quad * 8;
#pragma unroll
      for (int e = 0; e < 8; ++e) {
        W0[tI][kq][e] = f2bf(Wih0[o + e]);  Wh0f[tI][kq][e] = f2bf(Whh0[o + e]);
        W1[tI][kq][e] = f2bf(Wih1[o + e]);  Wh1f[tI][kq][e] = f2bf(Whh1[o + e]);
      }
    }
  }

  f32x4 h0reg[2] = {{0,0,0,0},{0,0,0,0}}, h1reg[2] = {{0,0,0,0},{0,0,0,0}};
  const f32x4 ZV = {0.f, 0.f, 0.f, 0.f};
  __syncthreads();
  const int aoff = nw * PAD + quad * 8;

  auto gates = [&](const f32x4 (&acc)[6], const f32x4 (&accn)[2], f32x4 (&hreg)[2],
                   const float (&brz)[4], const float (&bn)[4],
                   short* dhi, short* dlo) {
#pragma unroll
    for (int i = 0; i < 2; ++i) {
      const int c = u0 + i * 16 + nw;
#pragma unroll
      for (int rr = 0; rr < 4; ++rr) {
        float rv = fast_sigmoid(acc[i][rr] + brz[i]);
        float zv = fast_sigmoid(acc[2 + i][rr] + brz[2 + i]);
        float nv = fast_tanh((acc[4 + i][rr] + bn[i]) + rv * (accn[i][rr] + bn[2 + i]));
        float h = (1.f - zv) * nv + zv * hreg[i][rr];
        hreg[i][rr] = h;
        short hi = f2bf(h);
        const int row = quad * 4 + rr;
        dhi[row * PAD + c] = hi;
        dlo[row * PAD + c] = f2bf(h - bf2f(hi));
      }
    }
  };

  for (int t = 0; t < S_LEN; ++t) {
    const int pr = t & 1, pw = pr ^ 1;
    const int t1 = (t + 1 < S_LEN) ? t + 1 : t;
    bf16x8 xh, xl; load_x(t1, xh, xl);

    f32x4 acc[6], accn[2];
#pragma unroll
    for (int i = 0; i < 6; ++i) acc[i] = ZV;
#pragma unroll
    for (int i = 0; i < 2; ++i) accn[i] = ZV;
    bf16x8 a[4];
    loadA(a, &xbhi[pr][aoff]); mm6<false>(a, W0, acc, accn);
    loadA(a, &xblo[pr][aoff]); mm6<false>(a, W0, acc, accn);
    loadA(a, &h0hi[pr][aoff]); mm6<true >(a, Wh0f, acc, accn);
    loadA(a, &h0lo[pr][aoff]); mm6<true >(a, Wh0f, acc, accn);
    gates(acc, accn, h0reg, brz0, bn0, h0hi[pw], h0lo[pw]);
    __syncthreads();

#pragma unroll
    for (int i = 0; i < 6; ++i) acc[i] = ZV;
#pragma unroll
    for (int i = 0; i < 2; ++i) accn[i] = ZV;
    loadA(a, &h0hi[pw][aoff]); mm6<false>(a, W1, acc, accn);
    loadA(a, &h0lo[pw][aoff]); mm6<false>(a, W1, acc, accn);
    loadA(a, &h1hi[pr][aoff]); mm6<true >(a, Wh1f, acc, accn);
    loadA(a, &h1lo[pr][aoff]); mm6<true >(a, Wh1f, acc, accn);
    *(bf16x8*)&xbhi[pw][xsoff] = xh;
    *(bf16x8*)&xblo[pw][xsoff] = xl;
    gates(acc, accn, h1reg, brz1, bn1, h1hi[pw], h1lo[pw]);
    __syncthreads();
  }

  if (tid < 16 * 10) {
    const int b = tid / 10, c = tid % 10;
    float s = bout[c];
    const short* hh = &h1hi[0][b * PAD];
    const short* hl = &h1lo[0][b * PAD];
#pragma unroll 8
    for (int k = 0; k < HID; ++k)
      s += (bf2f(hh[k]) + bf2f(hl[k])) * Wout[c * HID + k];
    out[(size_t)(b0 + b) * 10 + c] = s;
  }
}

// ============================ Host =========================================
extern "C" void kernel_launch(void* const* d_in, const int* in_sizes, int n_in,
                              void* d_out, int out_size, void* d_ws, size_t ws_size,
                              hipStream_t stream) {
  (void)in_sizes; (void)n_in; (void)out_size;
  const float* x    = (const float*)d_in[0];
  const float* Wih0 = (const float*)d_in[1];
  const float* Whh0 = (const float*)d_in[2];
  const float* bih0 = (const float*)d_in[3];
  const float* bhh0 = (const float*)d_in[4];
  const float* Wih1 = (const float*)d_in[5];
  const float* Whh1 = (const float*)d_in[6];
  const float* bih1 = (const float*)d_in[7];
  const float* bhh1 = (const float*)d_in[8];
  const float* Wout = (const float*)d_in[9];
  const float* bout = (const float*)d_in[10];
  float* out = (float*)d_out;

  const size_t XPB = (size_t)M_TOT * G3 * sizeof(_Float16);  // 201 MB
  if (ws_size >= XPB) {
    xp0_gemm<<<dim3(M_TOT / 64), dim3(256), 0, stream>>>(
        x, Wih0, bih0, bhh0, (_Float16*)d_ws);
    gru2_rec<<<dim3(B_TOT / BC), dim3(512), 0, stream>>>(
        (const _Float16*)d_ws, Whh0, bhh0, Wih1, Whh1, bih1, bhh1, Wout, bout, out);
  } else {
    gru2_v1<<<dim3(B_TOT / 16), dim3(256), 0, stream>>>(
        x, Wih0, Whh0, bih0, bhh0, Wih1, Whh1, bih1, bhh1, Wout, bout, out);
  }
}